// Round 2
// baseline (27557.184 us; speedup 1.0000x reference)
//
#include <hip/hip_runtime.h>
#include <stdint.h>

typedef unsigned int u32;
typedef unsigned short u16;
typedef __attribute__((ext_vector_type(4))) float f32x4;
typedef __attribute__((ext_vector_type(8))) short bf16x8;

#define T_LEN 100
#define S_LEN 400
#define NB 16
#define HD 512
#define CTXD 1024
#define VOC 50000
#define K4H 2048
#define M_ALL 1600

static __device__ __forceinline__ float bf2f(u16 v) {
  union { u32 u; float f; } c; c.u = ((u32)v) << 16; return c.f;
}
static __device__ __forceinline__ u16 f2bf(float f) {
  union { float f; u32 u; } c; c.f = f;
  return (u16)((c.u + 0x7fffu + ((c.u >> 16) & 1u)) >> 16);
}
static __device__ __forceinline__ u32 pack2(float a, float b) {
  return (u32)f2bf(a) | ((u32)f2bf(b) << 16);
}
static __device__ __forceinline__ uint4 pack8(float4 a, float4 b) {
  return make_uint4(pack2(a.x, a.y), pack2(a.z, a.w), pack2(b.x, b.y), pack2(b.z, b.w));
}
static __device__ __forceinline__ float dot8(bf16x8 a, bf16x8 b) {
  float s = 0.f;
#pragma unroll
  for (int e = 0; e < 8; e++) s += bf2f((u16)a[e]) * bf2f((u16)b[e]);
  return s;
}
static __device__ __forceinline__ float sigm(float x) { return 1.f / (1.f + __expf(-x)); }
static __device__ __forceinline__ float tanh_(float x) {
  float e = __expf(2.f * x);
  return 1.f - 2.f / (e + 1.f);
}

__global__ void sentinel_kernel(float* out, float v) {
  if (threadIdx.x < NB) out[threadIdx.x] = v;
}

// ---------------- cast / fill kernels ----------------
__global__ __launch_bounds__(256) void cast_bf16(const float* __restrict__ src,
                                                 u16* __restrict__ dst, int n8) {
  int i = blockIdx.x * 256 + threadIdx.x;
  if (i >= n8) return;
  float4 a = *(const float4*)&src[i * 8];
  float4 b = *(const float4*)&src[i * 8 + 4];
  *(uint4*)&dst[i * 8] = pack8(a, b);
}

__global__ __launch_bounds__(256) void fill_feat_y(const float* __restrict__ yemb,
                                                   u16* __restrict__ feat) {
  int idx = blockIdx.x * 256 + threadIdx.x;
  if (idx >= M_ALL * 64) return;
  int m = idx >> 6, k8 = (idx & 63) << 3;
  float4 a = *(const float4*)&yemb[m * 512 + k8];
  float4 b = *(const float4*)&yemb[m * 512 + k8 + 4];
  *(uint4*)&feat[m * K4H + 1536 + k8] = pack8(a, b);
}

// ---------------- generic bf16 MFMA GEMM: C[M,N] = A[M,K] * B[N,K]^T + bias ----------------
// MODE 0: out bf16, +bias1[n].  MODE 1: out f32, +bias1[n]+bias2[n].
template <int MODE>
__global__ __launch_bounds__(256) void gemm_bf16(const u16* __restrict__ A,
                                                 const u16* __restrict__ Bw,
                                                 void* __restrict__ out,
                                                 const float* __restrict__ bias1,
                                                 const float* __restrict__ bias2,
                                                 int M, int N, int K) {
  __shared__ u16 As[64][40];
  __shared__ u16 Bs[64][40];
  int nb = N / 64;
  int m0 = (blockIdx.x / nb) * 64;
  int n0 = (blockIdx.x % nb) * 64;
  int tid = threadIdx.x;
  int lane = tid & 63;
  int w = tid >> 6;
  int wm = (w >> 1) * 32, wn = (w & 1) * 32;
  f32x4 acc[2][2] = {};
  int arow = tid >> 2, achk = (tid & 3) * 8;
  for (int k0 = 0; k0 < K; k0 += 32) {
    __syncthreads();
    *(uint4*)&As[arow][achk] = *(const uint4*)&A[(size_t)(m0 + arow) * K + k0 + achk];
    *(uint4*)&Bs[arow][achk] = *(const uint4*)&Bw[(size_t)(n0 + arow) * K + k0 + achk];
    __syncthreads();
    int r = lane & 15, kg = lane >> 4;
    bf16x8 a0 = *(const bf16x8*)&As[wm + r][kg * 8];
    bf16x8 a1 = *(const bf16x8*)&As[wm + 16 + r][kg * 8];
    bf16x8 b0 = *(const bf16x8*)&Bs[wn + r][kg * 8];
    bf16x8 b1 = *(const bf16x8*)&Bs[wn + 16 + r][kg * 8];
    acc[0][0] = __builtin_amdgcn_mfma_f32_16x16x32_bf16(a0, b0, acc[0][0], 0, 0, 0);
    acc[0][1] = __builtin_amdgcn_mfma_f32_16x16x32_bf16(a0, b1, acc[0][1], 0, 0, 0);
    acc[1][0] = __builtin_amdgcn_mfma_f32_16x16x32_bf16(a1, b0, acc[1][0], 0, 0, 0);
    acc[1][1] = __builtin_amdgcn_mfma_f32_16x16x32_bf16(a1, b1, acc[1][1], 0, 0, 0);
  }
  int col = lane & 15, rg = lane >> 4;
#pragma unroll
  for (int fi = 0; fi < 2; fi++)
#pragma unroll
    for (int fj = 0; fj < 2; fj++)
#pragma unroll
      for (int r = 0; r < 4; r++) {
        int m = m0 + wm + fi * 16 + rg * 4 + r;
        int n = n0 + wn + fj * 16 + col;
        float v = acc[fi][fj][r] + bias1[n];
        if constexpr (MODE == 1) {
          v += bias2[n];
          ((float*)out)[(size_t)m * N + n] = v;
        } else {
          ((u16*)out)[(size_t)m * N + n] = f2bf(v);
        }
      }
}

// ---------------- persistent recurrent decoder ----------------
struct PArgs {
  const u16 *pctx, *ctx, *Whh, *Wcomb, *Uxw, *Wxw;
  const float *xW, *bx, *uatt, *xmask, *ymask, *init_h, *init_c;
  float *h, *c, *h1, *c1, *q, *apn, *apd, *att;
  u16* feat;
  u32* bar;
};

static __device__ __forceinline__ void grid_barrier(u32* bar, int p) {
  __syncthreads();
  if (threadIdx.x == 0) {
    __builtin_amdgcn_fence(__ATOMIC_RELEASE, "agent");
    int g = blockIdx.x >> 4;
    u32* gcnt = bar + 32 + g * 32;
    u32* grel = bar + 32 + 512 + g * 32;
    u32 tgt = (u32)(p + 1) * 16u;
    u32 old = __hip_atomic_fetch_add(gcnt, 1u, __ATOMIC_ACQ_REL, __HIP_MEMORY_SCOPE_AGENT);
    if (old == tgt - 1u) {
      u32 rold = __hip_atomic_fetch_add(bar, 1u, __ATOMIC_ACQ_REL, __HIP_MEMORY_SCOPE_AGENT);
      if (rold == tgt - 1u) {
        for (int i = 0; i < 16; i++)
          __hip_atomic_store(bar + 32 + 512 + i * 32, (u32)(p + 1), __ATOMIC_RELEASE,
                             __HIP_MEMORY_SCOPE_AGENT);
      } else {
        while (__hip_atomic_load(grel, __ATOMIC_ACQUIRE, __HIP_MEMORY_SCOPE_AGENT) < (u32)(p + 1))
          __builtin_amdgcn_s_sleep(1);
      }
    } else {
      while (__hip_atomic_load(grel, __ATOMIC_ACQUIRE, __HIP_MEMORY_SCOPE_AGENT) < (u32)(p + 1))
        __builtin_amdgcn_s_sleep(1);
    }
    __builtin_amdgcn_fence(__ATOMIC_ACQUIRE, "agent");
  }
  __syncthreads();
}

__global__ __launch_bounds__(256, 1) void decoder_persistent(PArgs A) {
  extern __shared__ char smem[];
  u16* pctx_l = (u16*)smem;                  // 25*1024 bf16
  u16* ctx_l = (u16*)(smem + 51200);         // 25*1024 bf16
  u16* sbuf = (u16*)(smem + 102400);         // 16 rows * 1032 bf16
  u16* att2 = (u16*)(smem + 135424);         // 16 rows * 520 bf16
  float* q_l = (float*)(smem + 152064);      // 1024 f32
  float* ua_l = (float*)(smem + 156160);     // 1024 f32
  float* p_l = (float*)(smem + 160256);      // 32 f32
  float* xm_l = (float*)(smem + 160384);     // 32 f32

  const int tid = threadIdx.x;
  const int blk = blockIdx.x;
  const int bK = blk & 15;
  const int sq = blk >> 4;
  const int s0 = sq * 25;
  const int jBase = blk * 2;

  for (int idx = tid; idx < 25 * 128; idx += 256) {
    int i = idx >> 7, c8 = (idx & 127) << 3;
    *(uint4*)&pctx_l[i * 1024 + c8] = *(const uint4*)&A.pctx[((s0 + i) * NB + bK) * CTXD + c8];
    *(uint4*)&ctx_l[i * 1024 + c8] = *(const uint4*)&A.ctx[((s0 + i) * NB + bK) * CTXD + c8];
  }
  *(float4*)&ua_l[tid * 4] = *(const float4*)&A.uatt[tid * 4];
  if (tid < 25) xm_l[tid] = A.xmask[(s0 + tid) * NB + bK];
  if (tid < 32) {
    A.h[blk * 32 + tid] = A.init_h[blk * 32 + tid];
    A.c[blk * 32 + tid] = A.init_c[blk * 32 + tid];
  }
  int bidx = 0;
  grid_barrier(A.bar, bidx++);

  const int grp = tid >> 3, l8 = tid & 7;
  const int bb = grp >> 1;
  const int jj = jBase + (grp & 1);
  const int gg_ = l8 >> 1, hf = l8 & 1;
  const int baseLane = (tid & 63) & ~7;
  const int bq = tid >> 4, dl = (tid >> 2) & 3, qr = tid & 3;
  const int dq = blk * 4 + dl;
  const int wv = tid >> 6, lane = tid & 63;

  for (int ts = 0; ts < T_LEN; ts++) {
    float ymv = A.ymask[ts * NB + bb];
    // ---- phase A: LSTM1 gates + h1,c1 ----
    for (int idx = tid; idx < 1024; idx += 256) {
      int b = idx >> 6, c8 = (idx & 63) << 3;
      float4 a = *(const float4*)&A.h[b * 512 + c8];
      float4 bfv = *(const float4*)&A.h[b * 512 + c8 + 4];
      *(uint4*)&sbuf[b * 1032 + c8] = pack8(a, bfv);
    }
    __syncthreads();
    {
      const u16* wrow = A.Whh + (size_t)(gg_ * 512 + jj) * 512 + hf * 256;
      const u16* hrow = sbuf + bb * 1032 + hf * 256;
      float part = 0.f;
#pragma unroll 4
      for (int kk = 0; kk < 256; kk += 8)
        part += dot8(*(const bf16x8*)&wrow[kk], *(const bf16x8*)&hrow[kk]);
      part += __shfl_xor(part, 1);
      float gate = part + A.xW[(size_t)(ts * NB + bb) * K4H + gg_ * 512 + jj];
      float gi = __shfl(gate, baseLane + 0);
      float gf = __shfl(gate, baseLane + 2);
      float gG = __shfl(gate, baseLane + 4);
      float go = __shfl(gate, baseLane + 6);
      float c_old = A.c[bb * 512 + jj], h_old = A.h[bb * 512 + jj];
      float c1v = sigm(gf) * c_old + sigm(gi) * tanh_(gG);
      float h1v = sigm(go) * tanh_(c1v);
      h1v = ymv * h1v + (1.f - ymv) * h_old;
      c1v = ymv * c1v + (1.f - ymv) * c_old;
      if (l8 == 0) {
        A.h1[bb * 512 + jj] = h1v;
        A.c1[bb * 512 + jj] = c1v;
      }
    }
    grid_barrier(A.bar, bidx++);
    // ---- phase B: q = [h1,c1] @ Wcomb^T ----
    for (int idx = tid; idx < 2048; idx += 256) {
      int b = idx >> 7, c8 = (idx & 127) << 3;
      const float* src = (c8 < 512) ? &A.h1[b * 512 + c8] : &A.c1[b * 512 + c8 - 512];
      float4 a = *(const float4*)&src[0];
      float4 bfv = *(const float4*)&src[4];
      *(uint4*)&sbuf[b * 1032 + c8] = pack8(a, bfv);
    }
    __syncthreads();
    {
      const u16* wrow = A.Wcomb + (size_t)dq * 1024;
      float part = 0.f;
#pragma unroll 4
      for (int i = 0; i < 32; i++) {
        int k = (qr << 3) + (i << 5);
        part += dot8(*(const bf16x8*)&wrow[k], *(const bf16x8*)&sbuf[bq * 1032 + k]);
      }
      part += __shfl_xor(part, 1);
      part += __shfl_xor(part, 2);
      if (qr == 0) A.q[bq * 1024 + dq] = part;
    }
    grid_barrier(A.bar, bidx++);
    // ---- phase C: attention scores p[s] + partial att ----
    *(float4*)&q_l[tid * 4] = *(const float4*)&A.q[bK * 1024 + tid * 4];
    __syncthreads();
    for (int i = wv; i < 25; i += 4) {
      const u16* prow = pctx_l + i * 1024;
      int c0 = lane << 4;
      float s = 0.f;
#pragma unroll
      for (int half = 0; half < 2; half++) {
        bf16x8 pv = *(const bf16x8*)&prow[c0 + half * 8];
#pragma unroll
        for (int e = 0; e < 8; e++) {
          int c = c0 + half * 8 + e;
          s += tanh_(bf2f((u16)pv[e]) + q_l[c]) * ua_l[c];
        }
      }
#pragma unroll
      for (int off = 1; off < 64; off <<= 1) s += __shfl_xor(s, off);
      if (lane == 0) {
        float xm = xm_l[i];
        p_l[i] = __expf(s * xm) * xm;
      }
    }
    __syncthreads();
    {
      int c4 = tid << 2;
      float n0 = 0, n1 = 0, n2 = 0, n3 = 0;
#pragma unroll 5
      for (int i = 0; i < 25; i++) {
        float pv = p_l[i];
        uint2 ld = *(const uint2*)&ctx_l[i * 1024 + c4];
        n0 += pv * bf2f((u16)(ld.x & 0xffff));
        n1 += pv * bf2f((u16)(ld.x >> 16));
        n2 += pv * bf2f((u16)(ld.y & 0xffff));
        n3 += pv * bf2f((u16)(ld.y >> 16));
      }
      float4 o = {n0, n1, n2, n3};
      *(float4*)&A.apn[(sq * NB + bK) * CTXD + c4] = o;
      if (tid == 0) {
        float d = 0;
        for (int i = 0; i < 25; i++) d += p_l[i];
        A.apd[sq * NB + bK] = d;
      }
    }
    grid_barrier(A.bar, bidx++);
    // ---- phase D0: reduce att partials ----
    if (tid < 64) {
      int cc = sq * 64 + tid;
      float num = 0, den = 0;
#pragma unroll
      for (int s_ = 0; s_ < 16; s_++) {
        num += A.apn[(s_ * NB + bK) * CTXD + cc];
        den += A.apd[s_ * NB + bK];
      }
      float av = num / den;
      A.att[bK * CTXD + cc] = av;
      A.feat[(size_t)(ts * NB + bK) * K4H + 512 + cc] = f2bf(av);
    }
    grid_barrier(A.bar, bidx++);
    // ---- phase D1: second gate block + h2,c2 + feat ----
    for (int idx = tid; idx < 2048; idx += 256) {
      int b = idx >> 7, c8 = (idx & 127) << 3;
      float4 a = *(const float4*)&A.att[b * 1024 + c8];
      float4 bfv = *(const float4*)&A.att[b * 1024 + c8 + 4];
      uint4 pk = pack8(a, bfv);
      if (c8 < 512) *(uint4*)&sbuf[b * 1032 + 512 + c8] = pk;
      else *(uint4*)&att2[b * 520 + c8 - 512] = pk;
    }
    __syncthreads();
    {
      const u16* uxrow = A.Uxw + (size_t)(gg_ * 512 + jj) * 512 + hf * 256;
      const u16* h1row = sbuf + bb * 1032 + hf * 256;
      float part = 0.f;
#pragma unroll 4
      for (int kk = 0; kk < 256; kk += 8)
        part += dot8(*(const bf16x8*)&uxrow[kk], *(const bf16x8*)&h1row[kk]);
      const u16* wxrow = A.Wxw + (size_t)(gg_ * 512 + jj) * 1024 + hf * 512;
      const u16* arow = hf ? (att2 + bb * 520) : (sbuf + bb * 1032 + 512);
#pragma unroll 4
      for (int kk = 0; kk < 512; kk += 8)
        part += dot8(*(const bf16x8*)&wxrow[kk], *(const bf16x8*)&arow[kk]);
      part += __shfl_xor(part, 1);
      float pre = part + A.bx[gg_ * 512 + jj];
      float xi = __shfl(pre, baseLane + 0);
      float xf = __shfl(pre, baseLane + 2);
      float xo = __shfl(pre, baseLane + 4);
      float xc = __shfl(pre, baseLane + 6);
      float h1v = A.h1[bb * 512 + jj], c1v = A.c1[bb * 512 + jj];
      float c2 = sigm(xf) * c1v + sigm(xi) * tanh_(xc);
      float h2 = sigm(xo) * tanh_(c2);
      c2 = ymv * c2 + (1.f - ymv) * c1v;
      h2 = ymv * h2 + (1.f - ymv) * h1v;
      if (l8 == 0) {
        A.h[bb * 512 + jj] = h2;
        A.c[bb * 512 + jj] = c2;
        A.feat[(size_t)(ts * NB + bb) * K4H + jj] = f2bf(h2);
      }
    }
    grid_barrier(A.bar, bidx++);
  }
}

// ---------------- fused vocab GEMM + sum(exp) ----------------
__global__ __launch_bounds__(512, 1) void lse_gemm(const u16* __restrict__ feat,
                                                   const float* __restrict__ Wp,
                                                   const float* __restrict__ bp,
                                                   float* __restrict__ lse) {
  extern __shared__ char smem[];
  u16* Bl = (u16*)smem;  // [32][2056] bf16
  const int tid = threadIdx.x;
  const int n0 = blockIdx.x * 32;
  for (int n = 0; n < 32; n++) {
    int gn = n0 + n;
    float4 f = {0.f, 0.f, 0.f, 0.f};
    if (gn < VOC) f = *(const float4*)&Wp[(size_t)gn * K4H + tid * 4];
    uint2 t;
    t.x = pack2(f.x, f.y);
    t.y = pack2(f.z, f.w);
    *(uint2*)&Bl[n * 2056 + tid * 4] = t;
  }
  __syncthreads();
  const int w = tid >> 6, lane = tid & 63;
  const int r16 = lane & 15, kg = lane >> 4;
  int nf0 = n0 + r16, nf1 = n0 + 16 + r16;
  bool v0 = nf0 < VOC, v1 = nf1 < VOC;
  float bp0 = v0 ? bp[nf0] : 0.f;
  float bp1 = v1 ? bp[nf1] : 0.f;
  for (int q = w; q < 25; q += 8) {
    int mrow = q * 64;
    f32x4 acc[4][2] = {};
    for (int ks = 0; ks < 64; ks++) {
      bf16x8 b0 = *(const bf16x8*)&Bl[r16 * 2056 + ks * 32 + kg * 8];
      bf16x8 b1 = *(const bf16x8*)&Bl[(r16 + 16) * 2056 + ks * 32 + kg * 8];
#pragma unroll
      for (int s = 0; s < 4; s++) {
        bf16x8 a = *(const bf16x8*)&feat[(size_t)(mrow + s * 16 + r16) * K4H + ks * 32 + kg * 8];
        acc[s][0] = __builtin_amdgcn_mfma_f32_16x16x32_bf16(a, b0, acc[s][0], 0, 0, 0);
        acc[s][1] = __builtin_amdgcn_mfma_f32_16x16x32_bf16(a, b1, acc[s][1], 0, 0, 0);
      }
    }
#pragma unroll
    for (int s = 0; s < 4; s++) {
#pragma unroll
      for (int r = 0; r < 4; r++) {
        float e = (v0 ? __expf(acc[s][0][r] + bp0) : 0.f) +
                  (v1 ? __expf(acc[s][1][r] + bp1) : 0.f);
        e += __shfl_xor(e, 1);
        e += __shfl_xor(e, 2);
        e += __shfl_xor(e, 4);
        e += __shfl_xor(e, 8);
        if (r16 == 0) atomicAdd(&lse[mrow + s * 16 + kg * 4 + r], e);
      }
    }
  }
}

// ---------------- target logit + final cost ----------------
__global__ __launch_bounds__(256) void target_logit(const u16* __restrict__ feat,
                                                    const float* __restrict__ Wp,
                                                    const float* __restrict__ bp,
                                                    const int* __restrict__ yidx,
                                                    float* __restrict__ tlog) {
  int gw = (blockIdx.x * 256 + threadIdx.x) >> 6;
  int lane = threadIdx.x & 63;
  if (gw >= M_ALL) return;
  int yi = yidx[gw];
  const float* wrow = Wp + (size_t)yi * K4H;
  const u16* frow = feat + (size_t)gw * K4H;
  float s = 0.f;
#pragma unroll
  for (int i = 0; i < 4; i++) {
    int k = i * 512 + lane * 8;
    bf16x8 fv = *(const bf16x8*)&frow[k];
    float4 w0 = *(const float4*)&wrow[k];
    float4 w1 = *(const float4*)&wrow[k + 4];
    s += bf2f((u16)fv[0]) * w0.x + bf2f((u16)fv[1]) * w0.y + bf2f((u16)fv[2]) * w0.z +
         bf2f((u16)fv[3]) * w0.w + bf2f((u16)fv[4]) * w1.x + bf2f((u16)fv[5]) * w1.y +
         bf2f((u16)fv[6]) * w1.z + bf2f((u16)fv[7]) * w1.w;
  }
#pragma unroll
  for (int off = 1; off < 64; off <<= 1) s += __shfl_xor(s, off);
  if (lane == 0) tlog[gw] = s + bp[yi];
}

__global__ void finalize(const float* __restrict__ lse, const float* __restrict__ tlog,
                         const float* __restrict__ ymask, float* __restrict__ out) {
  int b = threadIdx.x;
  if (b < NB) {
    float sc = 0.f, sm = 0.f;
    for (int t = 0; t < T_LEN; t++) {
      int m = t * NB + b;
      float ym = ymask[m];
      sc += (logf(lse[m]) - tlog[m]) * ym;
      sm += ym;
    }
    out[b] = sc / sm;
  }
}

// ---------------- host launcher ----------------
extern "C" void kernel_launch(void* const* d_in, const int* in_sizes, int n_in,
                              void* d_out, int out_size, void* d_ws, size_t ws_size,
                              hipStream_t stream) {
  const float* y_emb = (const float*)d_in[0];
  const float* context = (const float*)d_in[1];
  const float* init_h = (const float*)d_in[2];
  const float* init_c = (const float*)d_in[3];
  const float* x_mask = (const float*)d_in[4];
  const float* y_mask = (const float*)d_in[5];
  const int* y_idx = (const int*)d_in[6];
  const float* W_ih = (const float*)d_in[7];
  const float* W_hh = (const float*)d_in[8];
  const float* b_ih = (const float*)d_in[9];
  const float* b_hh = (const float*)d_in[10];
  const float* Wx = (const float*)d_in[11];
  const float* Ux = (const float*)d_in[12];
  const float* bx = (const float*)d_in[13];
  const float* Wc_att = (const float*)d_in[14];
  const float* b_att = (const float*)d_in[15];
  const float* W_comb = (const float*)d_in[16];
  const float* U_att = (const float*)d_in[17];
  const float* Wp = (const float*)d_in[18];
  const float* bp = (const float*)d_in[19];

  // workspace layout (total 65,625,344 bytes)
  if (ws_size < 65700000ULL) {
    // not enough scratch: emit decodable sentinel (ws_size in MiB) and bail
    sentinel_kernel<<<1, 64, 0, stream>>>((float*)d_out, (float)(ws_size >> 20));
    return;
  }

  char* ws = (char*)d_ws;
  u32* bar = (u32*)ws;                       // 8192 B (zeroed)
  float* lse = (float*)(ws + 8192);          // 1600 f32 (zeroed)
  u16* pctx = (u16*)(ws + 16384);            // 6553600 bf16
  u16* ctxb = (u16*)(ws + 13123584);         // 6553600 bf16
  u16* Wcb = (u16*)(ws + 26230784);          // 1048576
  u16* yembb = (u16*)(ws + 28327936);        // 819200
  u16* Wihb = (u16*)(ws + 29966336);         // 1048576
  u16* Whhb = (u16*)(ws + 32063488);         // 1048576
  u16* Wcombb = (u16*)(ws + 34160640);       // 1048576
  u16* Uxb = (u16*)(ws + 38354944);          // 1048576
  u16* Wxb = (u16*)(ws + 40452096);          // 2097152
  float* xW = (float*)(ws + 44646400);       // 1600*2048 f32
  u16* feat = (u16*)(ws + 57753600);         // 1600*2048 bf16
  float* hws = (float*)(ws + 64307200);      // 4 * 8192 f32 (h,c,h1,c1)
  float* cws = hws + 8192;
  float* h1ws = hws + 16384;
  float* c1ws = hws + 24576;
  float* qws = (float*)(ws + 64438272);      // 16384 f32
  float* apn = (float*)(ws + 64503808);      // 262144 f32
  float* apd = (float*)(ws + 65552384);      // 256 f32
  float* attws = (float*)(ws + 65553408);    // 16384 f32
  float* tlog = (float*)(ws + 65618944);     // 1600 f32

  hipMemsetAsync(d_ws, 0, 16384, stream);

  cast_bf16<<<3200, 256, 0, stream>>>(context, ctxb, 819200);
  cast_bf16<<<512, 256, 0, stream>>>(Wc_att, Wcb, 131072);
  cast_bf16<<<400, 256, 0, stream>>>(y_emb, yembb, 102400);
  cast_bf16<<<512, 256, 0, stream>>>(W_ih, Wihb, 131072);
  cast_bf16<<<512, 256, 0, stream>>>(W_hh, Whhb, 131072);
  cast_bf16<<<512, 256, 0, stream>>>(W_comb, Wcombb, 131072);  // FIXED: was 262144 (4MB OOB read)
  cast_bf16<<<512, 256, 0, stream>>>(Ux, Uxb, 131072);
  cast_bf16<<<1024, 256, 0, stream>>>(Wx, Wxb, 262144);
  fill_feat_y<<<400, 256, 0, stream>>>(y_emb, feat);

  // pctx = context @ Wc_att^T + b_att   [6400,1024]
  gemm_bf16<0><<<1600, 256, 0, stream>>>(ctxb, Wcb, pctx, b_att, b_att, 6400, 1024, 1024);
  // xW = y_emb @ W_ih^T + b_ih + b_hh   [1600,2048]
  gemm_bf16<1><<<800, 256, 0, stream>>>(yembb, Wihb, xW, b_ih, b_hh, 1600, 2048, 512);

  PArgs a;
  a.pctx = pctx; a.ctx = ctxb; a.Whh = Whhb; a.Wcomb = Wcombb; a.Uxw = Uxb; a.Wxw = Wxb;
  a.xW = xW; a.bx = bx; a.uatt = U_att; a.xmask = x_mask; a.ymask = y_mask;
  a.init_h = init_h; a.init_c = init_c;
  a.h = hws; a.c = cws; a.h1 = h1ws; a.c1 = c1ws; a.q = qws;
  a.apn = apn; a.apd = apd; a.att = attws; a.feat = feat; a.bar = bar;

  hipFuncSetAttribute(reinterpret_cast<const void*>(decoder_persistent),
                      hipFuncAttributeMaxDynamicSharedMemorySize, 160512);
  decoder_persistent<<<256, 256, 160512, stream>>>(a);

  hipFuncSetAttribute(reinterpret_cast<const void*>(lse_gemm),
                      hipFuncAttributeMaxDynamicSharedMemorySize, 131584);
  lse_gemm<<<1563, 512, 131584, stream>>>(feat, Wp, bp, lse);

  target_logit<<<400, 256, 0, stream>>>(feat, Wp, bp, y_idx, tlog);
  finalize<<<1, 64, 0, stream>>>(lse, tlog, y_mask, (float*)d_out);
}

// Round 3
// 6602.386 us; speedup vs baseline: 4.1738x; 4.1738x over previous
//
#include <hip/hip_runtime.h>
#include <stdint.h>

typedef unsigned int u32;
typedef unsigned short u16;
typedef __attribute__((ext_vector_type(4))) float f32x4;
typedef __attribute__((ext_vector_type(8))) short bf16x8;

#define T_LEN 100
#define S_LEN 400
#define NB 16
#define HD 512
#define CTXD 1024
#define VOC 50000
#define K4H 2048
#define M_ALL 1600

static __device__ __forceinline__ float bf2f(u16 v) {
  union { u32 u; float f; } c; c.u = ((u32)v) << 16; return c.f;
}
static __device__ __forceinline__ u16 f2bf(float f) {
  union { float f; u32 u; } c; c.f = f;
  return (u16)((c.u + 0x7fffu + ((c.u >> 16) & 1u)) >> 16);
}
static __device__ __forceinline__ u32 pack2(float a, float b) {
  return (u32)f2bf(a) | ((u32)f2bf(b) << 16);
}
static __device__ __forceinline__ uint4 pack8(float4 a, float4 b) {
  return make_uint4(pack2(a.x, a.y), pack2(a.z, a.w), pack2(b.x, b.y), pack2(b.z, b.w));
}
static __device__ __forceinline__ float sigm(float x) { return 1.f / (1.f + __expf(-x)); }
static __device__ __forceinline__ float tanh_(float x) {
  float e = __expf(2.f * x);
  return 1.f - 2.f / (e + 1.f);
}

__global__ void sentinel_kernel(float* out, float v) {
  if (threadIdx.x < NB) out[threadIdx.x] = v;
}

// ---------------- cast / fill kernels ----------------
__global__ __launch_bounds__(256) void cast_bf16(const float* __restrict__ src,
                                                 u16* __restrict__ dst, int n8) {
  int i = blockIdx.x * 256 + threadIdx.x;
  if (i >= n8) return;
  float4 a = *(const float4*)&src[i * 8];
  float4 b = *(const float4*)&src[i * 8 + 4];
  *(uint4*)&dst[i * 8] = pack8(a, b);
}

__global__ __launch_bounds__(256) void fill_feat_y(const float* __restrict__ yemb,
                                                   u16* __restrict__ feat) {
  int idx = blockIdx.x * 256 + threadIdx.x;
  if (idx >= M_ALL * 64) return;
  int m = idx >> 6, k8 = (idx & 63) << 3;
  float4 a = *(const float4*)&yemb[m * 512 + k8];
  float4 b = *(const float4*)&yemb[m * 512 + k8 + 4];
  *(uint4*)&feat[m * K4H + 1536 + k8] = pack8(a, b);
}

// ---------------- generic bf16 MFMA GEMM: C[M,N] = A[M,K] * B[N,K]^T + bias ----------------
template <int MODE>
__global__ __launch_bounds__(256) void gemm_bf16(const u16* __restrict__ A,
                                                 const u16* __restrict__ Bw,
                                                 void* __restrict__ out,
                                                 const float* __restrict__ bias1,
                                                 const float* __restrict__ bias2,
                                                 int M, int N, int K) {
  __shared__ u16 As[64][40];
  __shared__ u16 Bs[64][40];
  int nb = N / 64;
  int m0 = (blockIdx.x / nb) * 64;
  int n0 = (blockIdx.x % nb) * 64;
  int tid = threadIdx.x;
  int lane = tid & 63;
  int w = tid >> 6;
  int wm = (w >> 1) * 32, wn = (w & 1) * 32;
  f32x4 acc[2][2] = {};
  int arow = tid >> 2, achk = (tid & 3) * 8;
  for (int k0 = 0; k0 < K; k0 += 32) {
    __syncthreads();
    *(uint4*)&As[arow][achk] = *(const uint4*)&A[(size_t)(m0 + arow) * K + k0 + achk];
    *(uint4*)&Bs[arow][achk] = *(const uint4*)&Bw[(size_t)(n0 + arow) * K + k0 + achk];
    __syncthreads();
    int r = lane & 15, kg = lane >> 4;
    bf16x8 a0 = *(const bf16x8*)&As[wm + r][kg * 8];
    bf16x8 a1 = *(const bf16x8*)&As[wm + 16 + r][kg * 8];
    bf16x8 b0 = *(const bf16x8*)&Bs[wn + r][kg * 8];
    bf16x8 b1 = *(const bf16x8*)&Bs[wn + 16 + r][kg * 8];
    acc[0][0] = __builtin_amdgcn_mfma_f32_16x16x32_bf16(a0, b0, acc[0][0], 0, 0, 0);
    acc[0][1] = __builtin_amdgcn_mfma_f32_16x16x32_bf16(a0, b1, acc[0][1], 0, 0, 0);
    acc[1][0] = __builtin_amdgcn_mfma_f32_16x16x32_bf16(a1, b0, acc[1][0], 0, 0, 0);
    acc[1][1] = __builtin_amdgcn_mfma_f32_16x16x32_bf16(a1, b1, acc[1][1], 0, 0, 0);
  }
  int col = lane & 15, rg = lane >> 4;
#pragma unroll
  for (int fi = 0; fi < 2; fi++)
#pragma unroll
    for (int fj = 0; fj < 2; fj++)
#pragma unroll
      for (int r = 0; r < 4; r++) {
        int m = m0 + wm + fi * 16 + rg * 4 + r;
        int n = n0 + wn + fj * 16 + col;
        float v = acc[fi][fj][r] + bias1[n];
        if constexpr (MODE == 1) {
          v += bias2[n];
          ((float*)out)[(size_t)m * N + n] = v;
        } else {
          ((u16*)out)[(size_t)m * N + n] = f2bf(v);
        }
      }
}

// ============ per-step kernels (4 launches per step; stream order = sync) ============

// K1: LSTM1. grid 16 blocks (j-slice of 32), 256 thr.
// gates[b, g*512+j] = h @ Whh^T + xW ; -> h1, c1
__global__ __launch_bounds__(256) void k1_lstm(const u16* __restrict__ Whh,
                                               const float* __restrict__ xW,
                                               const float* __restrict__ ym,
                                               const float* __restrict__ h,
                                               const float* __restrict__ c,
                                               float* __restrict__ h1,
                                               float* __restrict__ c1, int ts) {
  __shared__ u16 Al[16 * 520];
  __shared__ float gb[4][16][32];
  const int tid = threadIdx.x;
#pragma unroll
  for (int i = 0; i < 4; i++) {
    int idx = i * 256 + tid;
    int b = idx >> 6, k8 = (idx & 63) << 3;
    float4 a = *(const float4*)&h[b * 512 + k8];
    float4 bv = *(const float4*)&h[b * 512 + k8 + 4];
    *(uint4*)&Al[b * 520 + k8] = pack8(a, bv);
  }
  __syncthreads();
  const int lane = tid & 63, w = tid >> 6;  // w = gate
  const int r16 = lane & 15, kg = lane >> 4;
  const int j0 = blockIdx.x * 32;
  f32x4 acc0 = {}, acc1 = {};
  const size_t row0 = (size_t)(w * 512 + j0 + r16) * 512;
  const size_t row1 = (size_t)(w * 512 + j0 + 16 + r16) * 512;
#pragma unroll
  for (int ks = 0; ks < 16; ks++) {
    bf16x8 a = *(const bf16x8*)&Al[r16 * 520 + ks * 32 + kg * 8];
    bf16x8 b0 = *(const bf16x8*)&Whh[row0 + ks * 32 + kg * 8];
    bf16x8 b1 = *(const bf16x8*)&Whh[row1 + ks * 32 + kg * 8];
    acc0 = __builtin_amdgcn_mfma_f32_16x16x32_bf16(a, b0, acc0, 0, 0, 0);
    acc1 = __builtin_amdgcn_mfma_f32_16x16x32_bf16(a, b1, acc1, 0, 0, 0);
  }
#pragma unroll
  for (int r = 0; r < 4; r++) {
    gb[w][kg * 4 + r][r16] = acc0[r];
    gb[w][kg * 4 + r][16 + r16] = acc1[r];
  }
  __syncthreads();
#pragma unroll
  for (int i = 0; i < 2; i++) {
    int idx = i * 256 + tid;
    int b = idx >> 5, j = idx & 31;
    int n = j0 + j;
    const float* xw = &xW[(size_t)(ts * NB + b) * K4H];
    float gi = gb[0][b][j] + xw[n];
    float gf = gb[1][b][j] + xw[512 + n];
    float gg = gb[2][b][j] + xw[1024 + n];
    float go = gb[3][b][j] + xw[1536 + n];
    float ymv = ym[ts * NB + b];
    float c_old = c[b * 512 + n], h_old = h[b * 512 + n];
    float c1v = sigm(gf) * c_old + sigm(gi) * tanh_(gg);
    float h1v = sigm(go) * tanh_(c1v);
    h1v = ymv * h1v + (1.f - ymv) * h_old;
    c1v = ymv * c1v + (1.f - ymv) * c_old;
    h1[b * 512 + n] = h1v;
    c1[b * 512 + n] = c1v;
  }
}

// K2: q = [h1,c1] @ Wcomb^T. grid 16 blocks (64 q-dims each), 256 thr.
__global__ __launch_bounds__(256) void k2_q(const u16* __restrict__ Wcomb,
                                            const float* __restrict__ h1,
                                            const float* __restrict__ c1,
                                            float* __restrict__ q) {
  __shared__ u16 Al[16 * 1032];
  const int tid = threadIdx.x;
#pragma unroll
  for (int i = 0; i < 8; i++) {
    int idx = i * 256 + tid;
    int b = idx >> 7, k8 = (idx & 127) << 3;
    const float* src = (k8 < 512) ? &h1[b * 512 + k8] : &c1[b * 512 + k8 - 512];
    float4 a = *(const float4*)&src[0];
    float4 bv = *(const float4*)&src[4];
    *(uint4*)&Al[b * 1032 + k8] = pack8(a, bv);
  }
  __syncthreads();
  const int lane = tid & 63, w = tid >> 6;
  const int r16 = lane & 15, kg = lane >> 4;
  const int n0 = blockIdx.x * 64 + w * 16;
  f32x4 acc = {};
  const size_t row = (size_t)(n0 + r16) * 1024;
#pragma unroll
  for (int ks = 0; ks < 32; ks++) {
    bf16x8 a = *(const bf16x8*)&Al[r16 * 1032 + ks * 32 + kg * 8];
    bf16x8 b0 = *(const bf16x8*)&Wcomb[row + ks * 32 + kg * 8];
    acc = __builtin_amdgcn_mfma_f32_16x16x32_bf16(a, b0, acc, 0, 0, 0);
  }
#pragma unroll
  for (int r = 0; r < 4; r++) q[(kg * 4 + r) * 1024 + n0 + r16] = acc[r];
}

// K3: attention. grid 128 = 8 s-ranges x 16 batches, 256 thr.
// p = exp(u*xm)*xm (no max-sub); partial sums atomicAdd into attnum/attden[par].
__global__ __launch_bounds__(256) void k3_attn(const u16* __restrict__ pctx,
                                               const u16* __restrict__ ctxb,
                                               const float* __restrict__ q,
                                               const float* __restrict__ xmask,
                                               const float* __restrict__ uatt,
                                               float* __restrict__ attnum,
                                               float* __restrict__ attden, int par) {
  __shared__ float q_l[1024], ua_l[1024], p_l[56], xm_l[56];
  const int tid = threadIdx.x;
  const int b = blockIdx.x & 15;
  const int s0 = (blockIdx.x >> 4) * 50;
  *(float4*)&q_l[tid * 4] = *(const float4*)&q[b * 1024 + tid * 4];
  *(float4*)&ua_l[tid * 4] = *(const float4*)&uatt[tid * 4];
  if (tid < 50) xm_l[tid] = xmask[(s0 + tid) * NB + b];
  __syncthreads();
  const int w = tid >> 6, lane = tid & 63;
  for (int i = w; i < 50; i += 4) {
    const u16* prow = &pctx[((size_t)(s0 + i) * NB + b) * CTXD + lane * 16];
    float s = 0.f;
#pragma unroll
    for (int half = 0; half < 2; half++) {
      bf16x8 pv = *(const bf16x8*)&prow[half * 8];
#pragma unroll
      for (int e = 0; e < 8; e++) {
        int cc = lane * 16 + half * 8 + e;
        s += tanh_(bf2f((u16)pv[e]) + q_l[cc]) * ua_l[cc];
      }
    }
#pragma unroll
    for (int off = 1; off < 64; off <<= 1) s += __shfl_xor(s, off);
    if (lane == 0) {
      float xm = xm_l[i];
      p_l[i] = __expf(s * xm) * xm;
    }
  }
  __syncthreads();
  const int c4 = tid << 2;
  float n0 = 0, n1 = 0, n2 = 0, n3 = 0;
  for (int i = 0; i < 50; i++) {
    float pv = p_l[i];
    uint2 ld = *(const uint2*)&ctxb[((size_t)(s0 + i) * NB + b) * CTXD + c4];
    n0 += pv * bf2f((u16)(ld.x & 0xffff));
    n1 += pv * bf2f((u16)(ld.x >> 16));
    n2 += pv * bf2f((u16)(ld.y & 0xffff));
    n3 += pv * bf2f((u16)(ld.y >> 16));
  }
  float* dst = &attnum[par * 16384 + b * 1024 + c4];
  atomicAdd(dst + 0, n0);
  atomicAdd(dst + 1, n1);
  atomicAdd(dst + 2, n2);
  atomicAdd(dst + 3, n3);
  if (tid == 0) {
    float d = 0.f;
    for (int i = 0; i < 50; i++) d += p_l[i];
    atomicAdd(&attden[par * NB + b], d);
  }
}

// K4: gates2 + h2/c2 + feat writes + zero other-parity att slot.
// grid 32 blocks (j-slice of 16), 256 thr.
__global__ __launch_bounds__(256) void k4_gate2(const u16* __restrict__ Uxw,
                                                const u16* __restrict__ Wxw,
                                                const float* __restrict__ bx,
                                                float* __restrict__ attnum,
                                                float* __restrict__ attden,
                                                const float* __restrict__ h1,
                                                const float* __restrict__ c1,
                                                const float* __restrict__ ym,
                                                float* __restrict__ h,
                                                float* __restrict__ c,
                                                u16* __restrict__ feat, int ts, int par) {
  __shared__ u16 Al[16 * 1544];
  __shared__ float gb[4][16][16];
  const int tid = threadIdx.x;
  // stage h1 -> cols [0,512)
#pragma unroll
  for (int i = 0; i < 4; i++) {
    int idx = i * 256 + tid;
    int b = idx >> 6, k8 = (idx & 63) << 3;
    float4 a = *(const float4*)&h1[b * 512 + k8];
    float4 bv = *(const float4*)&h1[b * 512 + k8 + 4];
    *(uint4*)&Al[b * 1544 + k8] = pack8(a, bv);
  }
  // stage att = attnum/den -> cols [512,1536)
#pragma unroll
  for (int i = 0; i < 8; i++) {
    int idx = i * 256 + tid;
    int b = idx >> 7, c8 = (idx & 127) << 3;
    float rd = 1.f / attden[par * NB + b];
    const float* src = &attnum[par * 16384 + b * 1024 + c8];
    float4 a = *(const float4*)&src[0];
    float4 bv = *(const float4*)&src[4];
    a.x *= rd; a.y *= rd; a.z *= rd; a.w *= rd;
    bv.x *= rd; bv.y *= rd; bv.z *= rd; bv.w *= rd;
    *(uint4*)&Al[b * 1544 + 512 + c8] = pack8(a, bv);
  }
  __syncthreads();
  // feat att-part (blocks 0..15 handle batch = blockIdx.x)
  if (blockIdx.x < 16) {
#pragma unroll
    for (int r = 0; r < 4; r++) {
      int cc = r * 256 + tid;
      feat[(size_t)(ts * NB + blockIdx.x) * K4H + 512 + cc] = Al[blockIdx.x * 1544 + 512 + cc];
    }
  }
  const int lane = tid & 63, w = tid >> 6;  // w = gate (order i,f,o,c)
  const int r16 = lane & 15, kg = lane >> 4;
  const int j0 = blockIdx.x * 16;
  f32x4 acc = {};
  const size_t rowU = (size_t)(w * 512 + j0 + r16) * 512;
  const size_t rowW = (size_t)(w * 512 + j0 + r16) * 1024;
#pragma unroll
  for (int ks = 0; ks < 16; ks++) {
    bf16x8 a = *(const bf16x8*)&Al[r16 * 1544 + ks * 32 + kg * 8];
    bf16x8 b0 = *(const bf16x8*)&Uxw[rowU + ks * 32 + kg * 8];
    acc = __builtin_amdgcn_mfma_f32_16x16x32_bf16(a, b0, acc, 0, 0, 0);
  }
#pragma unroll
  for (int ks = 16; ks < 48; ks++) {
    bf16x8 a = *(const bf16x8*)&Al[r16 * 1544 + ks * 32 + kg * 8];
    bf16x8 b0 = *(const bf16x8*)&Wxw[rowW + (ks - 16) * 32 + kg * 8];
    acc = __builtin_amdgcn_mfma_f32_16x16x32_bf16(a, b0, acc, 0, 0, 0);
  }
#pragma unroll
  for (int r = 0; r < 4; r++) gb[w][kg * 4 + r][r16] = acc[r];
  __syncthreads();
  {
    int b = tid >> 4, j = tid & 15;
    int n = j0 + j;
    float xi = gb[0][b][j] + bx[n];
    float xf = gb[1][b][j] + bx[512 + n];
    float xo = gb[2][b][j] + bx[1024 + n];
    float xc = gb[3][b][j] + bx[1536 + n];
    float ymv = ym[ts * NB + b];
    float c1v = c1[b * 512 + n], h1v = h1[b * 512 + n];
    float c2 = sigm(xf) * c1v + sigm(xi) * tanh_(xc);
    float h2 = sigm(xo) * tanh_(c2);
    c2 = ymv * c2 + (1.f - ymv) * c1v;
    h2 = ymv * h2 + (1.f - ymv) * h1v;
    h[b * 512 + n] = h2;
    c[b * 512 + n] = c2;
    feat[(size_t)(ts * NB + b) * K4H + n] = f2bf(h2);
  }
  // zero other-parity att accumulators for step ts+1
  attnum[(par ^ 1) * 16384 + blockIdx.x * 512 + tid] = 0.f;
  attnum[(par ^ 1) * 16384 + blockIdx.x * 512 + 256 + tid] = 0.f;
  if (blockIdx.x == 0 && tid < NB) attden[(par ^ 1) * NB + tid] = 0.f;
}

// ---------------- fused vocab GEMM + sum(exp) ----------------
__global__ __launch_bounds__(512, 1) void lse_gemm(const u16* __restrict__ feat,
                                                   const float* __restrict__ Wp,
                                                   const float* __restrict__ bp,
                                                   float* __restrict__ lse) {
  extern __shared__ char smem[];
  u16* Bl = (u16*)smem;  // [32][2056] bf16
  const int tid = threadIdx.x;
  const int n0 = blockIdx.x * 32;
  for (int n = 0; n < 32; n++) {
    int gn = n0 + n;
    float4 f = {0.f, 0.f, 0.f, 0.f};
    if (gn < VOC) f = *(const float4*)&Wp[(size_t)gn * K4H + tid * 4];
    uint2 t;
    t.x = pack2(f.x, f.y);
    t.y = pack2(f.z, f.w);
    *(uint2*)&Bl[n * 2056 + tid * 4] = t;
  }
  __syncthreads();
  const int w = tid >> 6, lane = tid & 63;
  const int r16 = lane & 15, kg = lane >> 4;
  int nf0 = n0 + r16, nf1 = n0 + 16 + r16;
  bool v0 = nf0 < VOC, v1 = nf1 < VOC;
  float bp0 = v0 ? bp[nf0] : 0.f;
  float bp1 = v1 ? bp[nf1] : 0.f;
  for (int qq = w; qq < 25; qq += 8) {
    int mrow = qq * 64;
    f32x4 acc[4][2] = {};
    for (int ks = 0; ks < 64; ks++) {
      bf16x8 b0 = *(const bf16x8*)&Bl[r16 * 2056 + ks * 32 + kg * 8];
      bf16x8 b1 = *(const bf16x8*)&Bl[(r16 + 16) * 2056 + ks * 32 + kg * 8];
#pragma unroll
      for (int s = 0; s < 4; s++) {
        bf16x8 a = *(const bf16x8*)&feat[(size_t)(mrow + s * 16 + r16) * K4H + ks * 32 + kg * 8];
        acc[s][0] = __builtin_amdgcn_mfma_f32_16x16x32_bf16(a, b0, acc[s][0], 0, 0, 0);
        acc[s][1] = __builtin_amdgcn_mfma_f32_16x16x32_bf16(a, b1, acc[s][1], 0, 0, 0);
      }
    }
#pragma unroll
    for (int s = 0; s < 4; s++) {
#pragma unroll
      for (int r = 0; r < 4; r++) {
        float e = (v0 ? __expf(acc[s][0][r] + bp0) : 0.f) +
                  (v1 ? __expf(acc[s][1][r] + bp1) : 0.f);
        e += __shfl_xor(e, 1);
        e += __shfl_xor(e, 2);
        e += __shfl_xor(e, 4);
        e += __shfl_xor(e, 8);
        if (r16 == 0) atomicAdd(&lse[mrow + s * 16 + kg * 4 + r], e);
      }
    }
  }
}

// ---------------- target logit + final cost ----------------
__global__ __launch_bounds__(256) void target_logit(const u16* __restrict__ feat,
                                                    const float* __restrict__ Wp,
                                                    const float* __restrict__ bp,
                                                    const int* __restrict__ yidx,
                                                    float* __restrict__ tlog) {
  int gw = (blockIdx.x * 256 + threadIdx.x) >> 6;
  int lane = threadIdx.x & 63;
  if (gw >= M_ALL) return;
  int yi = yidx[gw];
  const float* wrow = Wp + (size_t)yi * K4H;
  const u16* frow = feat + (size_t)gw * K4H;
  float s = 0.f;
#pragma unroll
  for (int i = 0; i < 4; i++) {
    int k = i * 512 + lane * 8;
    bf16x8 fv = *(const bf16x8*)&frow[k];
    float4 w0 = *(const float4*)&wrow[k];
    float4 w1 = *(const float4*)&wrow[k + 4];
    s += bf2f((u16)fv[0]) * w0.x + bf2f((u16)fv[1]) * w0.y + bf2f((u16)fv[2]) * w0.z +
         bf2f((u16)fv[3]) * w0.w + bf2f((u16)fv[4]) * w1.x + bf2f((u16)fv[5]) * w1.y +
         bf2f((u16)fv[6]) * w1.z + bf2f((u16)fv[7]) * w1.w;
  }
#pragma unroll
  for (int off = 1; off < 64; off <<= 1) s += __shfl_xor(s, off);
  if (lane == 0) tlog[gw] = s + bp[yi];
}

__global__ void finalize(const float* __restrict__ lse, const float* __restrict__ tlog,
                         const float* __restrict__ ymask, float* __restrict__ out) {
  int b = threadIdx.x;
  if (b < NB) {
    float sc = 0.f, sm = 0.f;
    for (int t = 0; t < T_LEN; t++) {
      int m = t * NB + b;
      float ym = ymask[m];
      sc += (logf(lse[m]) - tlog[m]) * ym;
      sm += ym;
    }
    out[b] = sc / sm;
  }
}

// ---------------- host launcher ----------------
extern "C" void kernel_launch(void* const* d_in, const int* in_sizes, int n_in,
                              void* d_out, int out_size, void* d_ws, size_t ws_size,
                              hipStream_t stream) {
  const float* y_emb = (const float*)d_in[0];
  const float* context = (const float*)d_in[1];
  const float* init_h = (const float*)d_in[2];
  const float* init_c = (const float*)d_in[3];
  const float* x_mask = (const float*)d_in[4];
  const float* y_mask = (const float*)d_in[5];
  const int* y_idx = (const int*)d_in[6];
  const float* W_ih = (const float*)d_in[7];
  const float* W_hh = (const float*)d_in[8];
  const float* b_ih = (const float*)d_in[9];
  const float* b_hh = (const float*)d_in[10];
  const float* Wx = (const float*)d_in[11];
  const float* Ux = (const float*)d_in[12];
  const float* bx = (const float*)d_in[13];
  const float* Wc_att = (const float*)d_in[14];
  const float* b_att = (const float*)d_in[15];
  const float* W_comb = (const float*)d_in[16];
  const float* U_att = (const float*)d_in[17];
  const float* Wp = (const float*)d_in[18];
  const float* bp = (const float*)d_in[19];

  if (ws_size < 50000000ULL) {
    sentinel_kernel<<<1, 64, 0, stream>>>((float*)d_out, (float)(ws_size >> 20));
    return;
  }

  char* ws = (char*)d_ws;
  float* lse = (float*)(ws + 0);             // 1600 f32 (zeroed)
  float* attnum = (float*)(ws + 8192);       // 2 x 16384 f32 (zeroed)
  float* attden = (float*)(ws + 139264);     // 2 x 16 f32 (zeroed)
  float* tlog = (float*)(ws + 139776);       // 1600 f32
  u16* pctx = (u16*)(ws + 147456);           // 6,553,600
  u16* ctxb = (u16*)(ws + 6701056);          // 6,553,600
  u16* Wcb = (u16*)(ws + 13254656);          // 2,097,152
  u16* yembb = (u16*)(ws + 15351808);        // 1,638,400
  u16* Wihb = (u16*)(ws + 16990208);         // 2,097,152
  u16* Whhb = (u16*)(ws + 19087360);         // 2,097,152
  u16* Wcombb = (u16*)(ws + 21184512);       // 2,097,152
  u16* Uxb = (u16*)(ws + 23281664);          // 2,097,152
  u16* Wxb = (u16*)(ws + 25378816);          // 4,194,304
  float* xW = (float*)(ws + 29573120);       // 13,107,200
  u16* feat = (u16*)(ws + 42680320);         // 6,553,600
  float* hbuf = (float*)(ws + 49233920);     // 32,768
  float* cbuf = (float*)(ws + 49266688);     // 32,768
  float* h1buf = (float*)(ws + 49299456);    // 32,768
  float* c1buf = (float*)(ws + 49332224);    // 32,768
  float* qbuf = (float*)(ws + 49364992);     // 65,536

  hipMemsetAsync(ws, 0, 139776, stream);  // lse + attnum[2] + attden[2]

  cast_bf16<<<3200, 256, 0, stream>>>(context, ctxb, 819200);
  cast_bf16<<<512, 256, 0, stream>>>(Wc_att, Wcb, 131072);
  cast_bf16<<<400, 256, 0, stream>>>(y_emb, yembb, 102400);
  cast_bf16<<<512, 256, 0, stream>>>(W_ih, Wihb, 131072);
  cast_bf16<<<512, 256, 0, stream>>>(W_hh, Whhb, 131072);
  cast_bf16<<<512, 256, 0, stream>>>(W_comb, Wcombb, 131072);
  cast_bf16<<<512, 256, 0, stream>>>(Ux, Uxb, 131072);
  cast_bf16<<<1024, 256, 0, stream>>>(Wx, Wxb, 262144);
  fill_feat_y<<<400, 256, 0, stream>>>(y_emb, feat);

  // pctx = context @ Wc_att^T + b_att   [6400,1024]
  gemm_bf16<0><<<1600, 256, 0, stream>>>(ctxb, Wcb, pctx, b_att, b_att, 6400, 1024, 1024);
  // xW = y_emb @ W_ih^T + b_ih + b_hh   [1600,2048]
  gemm_bf16<1><<<800, 256, 0, stream>>>(yembb, Wihb, xW, b_ih, b_hh, 1600, 2048, 512);

  hipMemcpyAsync(hbuf, init_h, 32768, hipMemcpyDeviceToDevice, stream);
  hipMemcpyAsync(cbuf, init_c, 32768, hipMemcpyDeviceToDevice, stream);

  for (int ts = 0; ts < T_LEN; ts++) {
    int par = ts & 1;
    k1_lstm<<<16, 256, 0, stream>>>(Whhb, xW, y_mask, hbuf, cbuf, h1buf, c1buf, ts);
    k2_q<<<16, 256, 0, stream>>>(Wcombb, h1buf, c1buf, qbuf);
    k3_attn<<<128, 256, 0, stream>>>(pctx, ctxb, qbuf, x_mask, U_att, attnum, attden, par);
    k4_gate2<<<32, 256, 0, stream>>>(Uxb, Wxb, bx, attnum, attden, h1buf, c1buf, y_mask,
                                     hbuf, cbuf, feat, ts, par);
  }

  hipFuncSetAttribute(reinterpret_cast<const void*>(lse_gemm),
                      hipFuncAttributeMaxDynamicSharedMemorySize, 131584);
  lse_gemm<<<1563, 512, 131584, stream>>>(feat, Wp, bp, lse);

  target_logit<<<400, 256, 0, stream>>>(feat, Wp, bp, y_idx, tlog);
  finalize<<<1, 64, 0, stream>>>(lse, tlog, y_mask, (float*)d_out);
}